// Round 4
// baseline (140.420 us; speedup 1.0000x reference)
//
#include <hip/hip_runtime.h>
#include <hip/hip_bf16.h>

// Problem constants
#define N_  4
#define CI  4
#define CO  8
#define HH  512
#define WW  512
#define RK  4

// x[n][i][h][w]   : ((n*CI + i)*HH + h)*WW + w
// L[o][i][p][r]   : ((o*CI + i)*HH + p)*RK + r   (float4-aligned per p)
// Rt[n][o][h]     : (n*CO + o)*HH + h
// Ct[n][o][w]     : (n*CO + o)*WW + w
// out[n][o][h][w] : ((n*CO + o)*HH + h)*WW + w

__device__ __forceinline__ float dot4(float4 a, float4 b) {
    return fmaf(a.x, b.x, fmaf(a.y, b.y, fmaf(a.z, b.z, a.w * b.w)));
}

// R~[n,o,h] += sum_{w in 16-chunk} x[n,i,h,w] * dot4(L[o,i,h,:], L[o,i,w,:])
// grid (32 wchunks, 8 htiles, 4 n), block 256 = 64 h-lanes x 4 i-strips
// (i = strip: per-thread work is 4x smaller than round-2; lw addresses are
//  block-uniform -> scalar loads)
__global__ __launch_bounds__(256) void rowsum_kernel(
        const float* __restrict__ x, const float* __restrict__ L,
        float* __restrict__ Rt) {
    const int lane = threadIdx.x & 63;   // h offset within tile
    const int i    = threadIdx.x >> 6;   // input channel
    const int h  = blockIdx.y * 64 + lane;
    const int wb = blockIdx.x * 16;
    const int n  = blockIdx.z;

    // per-lane Lh fragments (distinct h per lane -> vector loads)
    float4 Lh[CO];
#pragma unroll
    for (int o = 0; o < CO; ++o)
        Lh[o] = *reinterpret_cast<const float4*>(&L[((o*CI + i)*HH + h)*RK]);

    // 64 contiguous bytes of this row
    const float* xrow = &x[((n*CI + i)*HH + h)*WW + wb];
    float4 xq[4];
#pragma unroll
    for (int q = 0; q < 4; ++q)
        xq[q] = *reinterpret_cast<const float4*>(&xrow[q * 4]);

    float acc[CO];
#pragma unroll
    for (int o = 0; o < CO; ++o) acc[o] = 0.f;

#pragma unroll
    for (int q = 0; q < 4; ++q) {
#pragma unroll
        for (int c = 0; c < 4; ++c) {
            const int w = wb + q * 4 + c;
            const float xv = (c == 0) ? xq[q].x : (c == 1) ? xq[q].y
                           : (c == 2) ? xq[q].z : xq[q].w;
#pragma unroll
            for (int o = 0; o < CO; ++o) {
                // block-uniform address -> scalar (s_load) candidate
                float4 lw = *reinterpret_cast<const float4*>(&L[((o*CI + i)*HH + w)*RK]);
                acc[o] = fmaf(xv, dot4(Lh[o], lw), acc[o]);
            }
        }
    }
#pragma unroll
    for (int o = 0; o < CO; ++o)
        atomicAdd(&Rt[(n*CO + o)*HH + h], acc[o]);
}

// C~[n,o,w] += sum_{h in 16-chunk} x[n,i,h,w] * dot4(L[o,i,h,:], L[o,i,w,:])
// grid (32 hchunks, 8 wtiles, 4 n), block 256 = 64 w-lanes x 4 i-strips
__global__ __launch_bounds__(256) void colsum_kernel(
        const float* __restrict__ x, const float* __restrict__ L,
        float* __restrict__ Ct) {
    const int lane = threadIdx.x & 63;   // w offset within tile
    const int i    = threadIdx.x >> 6;   // input channel
    const int w  = blockIdx.y * 64 + lane;
    const int hb = blockIdx.x * 16;
    const int n  = blockIdx.z;

    float4 Lw[CO];
#pragma unroll
    for (int o = 0; o < CO; ++o)
        Lw[o] = *reinterpret_cast<const float4*>(&L[((o*CI + i)*HH + w)*RK]);

    const float* xcol = &x[((n*CI + i)*HH)*WW + w];

    float acc[CO];
#pragma unroll
    for (int o = 0; o < CO; ++o) acc[o] = 0.f;

#pragma unroll
    for (int k = 0; k < 16; ++k) {
        const int h = hb + k;
        const float xv = xcol[h * WW];   // coalesced across lanes
#pragma unroll
        for (int o = 0; o < CO; ++o) {
            // block-uniform address -> scalar (s_load) candidate
            float4 lh = *reinterpret_cast<const float4*>(&L[((o*CI + i)*HH + h)*RK]);
            acc[o] = fmaf(xv, dot4(Lw[o], lh), acc[o]);
        }
    }
#pragma unroll
    for (int o = 0; o < CO; ++o)
        atomicAdd(&Ct[(n*CO + o)*WW + w], acc[o]);
}

// out[n,o,h,w] = R~[n,o,h] + C~[n,o,w] + bias[o] - sum_i x[n,i,h,w]*dot4(Lh,Lw)
// grid (2 wtiles, 128 htiles, 4 n), block 256 (one w per thread, 4 h rows, all o)
__global__ __launch_bounds__(256) void final_kernel(
        const float* __restrict__ x, const float* __restrict__ L,
        const float* __restrict__ Rt, const float* __restrict__ Ct,
        const float* __restrict__ bias, float* __restrict__ out) {
    const int w  = blockIdx.x * 256 + threadIdx.x;
    const int h0 = blockIdx.y * 4;
    const int n  = blockIdx.z;

    // x held in registers: read once, reused by all 8 output channels
    float xv[CI][4];
#pragma unroll
    for (int i = 0; i < CI; ++i)
#pragma unroll
        for (int hh = 0; hh < 4; ++hh)
            xv[i][hh] = x[((n*CI + i)*HH + h0 + hh)*WW + w];

#pragma unroll 2
    for (int o = 0; o < CO; ++o) {
        float4 Lw[CI];
#pragma unroll
        for (int i = 0; i < CI; ++i)
            Lw[i] = *reinterpret_cast<const float4*>(&L[((o*CI + i)*HH + w)*RK]);
        const float cv = Ct[(n*CO + o)*WW + w];
        const float bz = bias[o];
        const float* rrow = &Rt[(n*CO + o)*HH + h0];
        float* orow = &out[((n*CO + o)*HH + h0)*WW + w];
#pragma unroll
        for (int hh = 0; hh < 4; ++hh) {
            float s = rrow[hh] + cv + bz;
#pragma unroll
            for (int i = 0; i < CI; ++i) {
                // block-uniform address -> scalar (s_load) candidate
                float4 lh = *reinterpret_cast<const float4*>(&L[((o*CI + i)*HH + h0 + hh)*RK]);
                s = fmaf(-xv[i][hh], dot4(lh, Lw[i]), s);
            }
            orow[hh * WW] = s;
        }
    }
}

extern "C" void kernel_launch(void* const* d_in, const int* in_sizes, int n_in,
                              void* d_out, int out_size, void* d_ws, size_t ws_size,
                              hipStream_t stream) {
    const float* x    = (const float*)d_in[0];
    const float* L    = (const float*)d_in[1];
    const float* bias = (const float*)d_in[2];
    float* out = (float*)d_out;

    float* Rt = (float*)d_ws;                    // N*CO*H = 16384 floats
    float* Ct = Rt + N_*CO*HH;                   // N*CO*W = 16384 floats

    hipMemsetAsync(d_ws, 0, 2 * N_*CO*HH * sizeof(float), stream);

    rowsum_kernel<<<dim3(32, 8, 4), 256, 0, stream>>>(x, L, Rt);
    colsum_kernel<<<dim3(32, 8, 4), 256, 0, stream>>>(x, L, Ct);
    final_kernel<<<dim3(2, 128, 4), 256, 0, stream>>>(x, L, Rt, Ct, bias, out);
}

// Round 5
// 91.705 us; speedup vs baseline: 1.5312x; 1.5312x over previous
//
#include <hip/hip_runtime.h>
#include <hip/hip_bf16.h>

// Problem constants
#define N_   4
#define CI   4
#define CO   8
#define HH   512
#define WW   512
#define W4   (WW/4)
#define RK   4
#define TILE 64
#define OG   4   // output channels per block (2 groups)

// x[n][i][h][w]  float4-viewed over w
// L[o][i][p][r]  float4 per p (RK=4)
// Rp[n][wt][o][h] : partial row sums (summed over this wt's 64 w)
// Cp[n][ht][o][w] : partial col sums (summed over this ht's 64 h)

__device__ __forceinline__ float dot4(float4 a, float4 b) {
    return fmaf(a.x, b.x, fmaf(a.y, b.y, fmaf(a.z, b.z, a.w * b.w)));
}

// Kernel A: per-tile partial row/col sums of p[n,o,h,w] = sum_i x * dot4(Lh,Lw).
// grid (8 wt, 8 ht, 8 = n*2+og), block 256 = 16 tx (w) x 16 ty (h), 4x4 pts/thread
__global__ __launch_bounds__(256) void rowcol_kernel(
        const float4* __restrict__ x4, const float4* __restrict__ L4,
        float* __restrict__ Rp, float* __restrict__ Cp) {
    __shared__ float4 Lhs[16 * 64];        // [o_l*4+i][p]  16 KB
    __shared__ float4 Lws[16 * 64];        // 16 KB
    __shared__ float4 redq[16 * 65];       // padded transpose-reduce buffer 16.6 KB
    float* red = (float*)redq;

    const int t  = threadIdx.x;
    const int tx = t & 15, ty = t >> 4;
    const int wt = blockIdx.x, ht = blockIdx.y;
    const int n  = blockIdx.z >> 1, og = blockIdx.z & 1;
    const int h0 = ht * TILE, w0 = wt * TILE;

    // Stage L fragments for this tile (4 o's) into LDS — coalesced 1 KB rows.
#pragma unroll
    for (int k = 0; k < 4; ++k) {
        const int idx = t + k * 256;
        const int oi = idx >> 6, p = idx & 63;
        const int o = og * OG + (oi >> 2), i = oi & 3;
        const int base = (o * CI + i) * HH;
        Lhs[oi * 64 + p] = L4[base + h0 + p];
        Lws[oi * 64 + p] = L4[base + w0 + p];
    }

    // x micro-tile: 4h x 4w per thread, all 4 input channels (registers).
    float4 xr[CI][4];
#pragma unroll
    for (int i = 0; i < CI; ++i)
#pragma unroll
        for (int lh = 0; lh < 4; ++lh)
            xr[i][lh] = x4[((n * CI + i) * HH + h0 + ty * 4 + lh) * W4 + (w0 >> 2) + tx];

    __syncthreads();

    float4 rowA[OG], colA[OG];
#pragma unroll
    for (int ol = 0; ol < OG; ++ol) {
        float ra[4] = {0.f, 0.f, 0.f, 0.f};
        float4 ca = make_float4(0.f, 0.f, 0.f, 0.f);
#pragma unroll
        for (int i = 0; i < CI; ++i) {
            const int oi = ol * 4 + i;
            const float4 lw0 = Lws[oi * 64 + tx * 4 + 0];
            const float4 lw1 = Lws[oi * 64 + tx * 4 + 1];
            const float4 lw2 = Lws[oi * 64 + tx * 4 + 2];
            const float4 lw3 = Lws[oi * 64 + tx * 4 + 3];
#pragma unroll
            for (int lh = 0; lh < 4; ++lh) {
                const float4 lhv = Lhs[oi * 64 + ty * 4 + lh];
                const float4 xv  = xr[i][lh];
                const float p0 = xv.x * dot4(lhv, lw0);
                const float p1 = xv.y * dot4(lhv, lw1);
                const float p2 = xv.z * dot4(lhv, lw2);
                const float p3 = xv.w * dot4(lhv, lw3);
                ra[lh] += (p0 + p1) + (p2 + p3);
                ca.x += p0; ca.y += p1; ca.z += p2; ca.w += p3;
            }
        }
        rowA[ol] = make_float4(ra[0], ra[1], ra[2], ra[3]);
        colA[ol] = ca;
    }

    // --- rows: reduce over 16 tx via padded LDS transpose, store partials ---
#pragma unroll
    for (int ol = 0; ol < OG; ++ol)
        redq[tx * 65 + ol * 16 + ty] = rowA[ol];
    __syncthreads();
    {
        const int o = t >> 6, e = t & 63;          // o in [0,4), e = h offset
        const int tyy = e >> 2, lh = e & 3;
        float s = 0.f;
#pragma unroll
        for (int k = 0; k < 16; ++k)
            s += red[(k * 65 + o * 16 + tyy) * 4 + lh];
        Rp[((n * 8 + wt) * CO + og * OG + o) * HH + h0 + e] = s;
    }
    __syncthreads();
    // --- cols: reduce over 16 ty ---
#pragma unroll
    for (int ol = 0; ol < OG; ++ol)
        redq[ty * 65 + ol * 16 + tx] = colA[ol];
    __syncthreads();
    {
        const int o = t >> 6, e = t & 63;          // e = w offset
        const int txx = e >> 2, lw = e & 3;
        float s = 0.f;
#pragma unroll
        for (int k = 0; k < 16; ++k)
            s += red[(k * 65 + o * 16 + txx) * 4 + lw];
        Cp[((n * 8 + ht) * CO + og * OG + o) * WW + w0 + e] = s;
    }
}

// Kernel B: out = Rt + Ct + bias - p (p recomputed from LDS-staged L).
// grid (8 wt, 8 ht, 8 = n*2+og), block 256
__global__ __launch_bounds__(256) void final_kernel(
        const float4* __restrict__ x4, const float4* __restrict__ L4,
        const float* __restrict__ Rp, const float* __restrict__ Cp,
        const float* __restrict__ bias, float4* __restrict__ out4) {
    __shared__ float4 Lhs[16 * 64];
    __shared__ float4 Lws[16 * 64];
    __shared__ float  Rs[OG * 64];   // full row sums for this h-tile
    __shared__ float  Cs[OG * 64];   // full col sums for this w-tile

    const int t  = threadIdx.x;
    const int tx = t & 15, ty = t >> 4;
    const int wt = blockIdx.x, ht = blockIdx.y;
    const int n  = blockIdx.z >> 1, og = blockIdx.z & 1;
    const int h0 = ht * TILE, w0 = wt * TILE;

#pragma unroll
    for (int k = 0; k < 4; ++k) {
        const int idx = t + k * 256;
        const int oi = idx >> 6, p = idx & 63;
        const int o = og * OG + (oi >> 2), i = oi & 3;
        const int base = (o * CI + i) * HH;
        Lhs[oi * 64 + p] = L4[base + h0 + p];
        Lws[oi * 64 + p] = L4[base + w0 + p];
    }

    // Sum the 8 partials for this tile's rows/cols into LDS (coalesced reads).
    {
        const int o = t >> 6, e = t & 63;
        float sr = 0.f, sc = 0.f;
#pragma unroll
        for (int k = 0; k < 8; ++k) {
            sr += Rp[((n * 8 + k) * CO + og * OG + o) * HH + h0 + e];
            sc += Cp[((n * 8 + k) * CO + og * OG + o) * WW + w0 + e];
        }
        Rs[o * 64 + e] = sr;
        Cs[o * 64 + e] = sc;
    }

    float4 xr[CI][4];
#pragma unroll
    for (int i = 0; i < CI; ++i)
#pragma unroll
        for (int lh = 0; lh < 4; ++lh)
            xr[i][lh] = x4[((n * CI + i) * HH + h0 + ty * 4 + lh) * W4 + (w0 >> 2) + tx];

    __syncthreads();

#pragma unroll
    for (int ol = 0; ol < OG; ++ol) {
        const int o = og * OG + ol;
        float pacc[4][4];
#pragma unroll
        for (int a = 0; a < 4; ++a)
#pragma unroll
            for (int b = 0; b < 4; ++b) pacc[a][b] = 0.f;

#pragma unroll
        for (int i = 0; i < CI; ++i) {
            const int oi = ol * 4 + i;
            const float4 lw0 = Lws[oi * 64 + tx * 4 + 0];
            const float4 lw1 = Lws[oi * 64 + tx * 4 + 1];
            const float4 lw2 = Lws[oi * 64 + tx * 4 + 2];
            const float4 lw3 = Lws[oi * 64 + tx * 4 + 3];
#pragma unroll
            for (int lh = 0; lh < 4; ++lh) {
                const float4 lhv = Lhs[oi * 64 + ty * 4 + lh];
                const float4 xv  = xr[i][lh];
                pacc[lh][0] = fmaf(xv.x, dot4(lhv, lw0), pacc[lh][0]);
                pacc[lh][1] = fmaf(xv.y, dot4(lhv, lw1), pacc[lh][1]);
                pacc[lh][2] = fmaf(xv.z, dot4(lhv, lw2), pacc[lh][2]);
                pacc[lh][3] = fmaf(xv.w, dot4(lhv, lw3), pacc[lh][3]);
            }
        }

        const float bz = bias[o];
        const float c0 = Cs[ol * 64 + tx * 4 + 0] + bz;
        const float c1 = Cs[ol * 64 + tx * 4 + 1] + bz;
        const float c2 = Cs[ol * 64 + tx * 4 + 2] + bz;
        const float c3 = Cs[ol * 64 + tx * 4 + 3] + bz;
#pragma unroll
        for (int lh = 0; lh < 4; ++lh) {
            const float r = Rs[ol * 64 + ty * 4 + lh];
            float4 res;
            res.x = r + c0 - pacc[lh][0];
            res.y = r + c1 - pacc[lh][1];
            res.z = r + c2 - pacc[lh][2];
            res.w = r + c3 - pacc[lh][3];
            out4[((n * CO + o) * HH + h0 + ty * 4 + lh) * W4 + (w0 >> 2) + tx] = res;
        }
    }
}

extern "C" void kernel_launch(void* const* d_in, const int* in_sizes, int n_in,
                              void* d_out, int out_size, void* d_ws, size_t ws_size,
                              hipStream_t stream) {
    const float4* x4  = (const float4*)d_in[0];
    const float4* L4  = (const float4*)d_in[1];
    const float* bias = (const float*)d_in[2];
    float4* out4 = (float4*)d_out;

    float* Rp = (float*)d_ws;                 // [4][8][8][512] = 131072 floats
    float* Cp = Rp + N_ * 8 * CO * HH;        // [4][8][8][512]
    // Every slot of Rp/Cp is written exactly once by rowcol_kernel -> no memset.

    dim3 grid(8, 8, 8);
    rowcol_kernel<<<grid, 256, 0, stream>>>(x4, L4, Rp, Cp);
    final_kernel<<<grid, 256, 0, stream>>>(x4, L4, Rp, Cp, bias, out4);
}